// Round 1
// baseline (617.084 us; speedup 1.0000x reference)
//
#include <hip/hip_runtime.h>
#include <hip/hip_bf16.h>

// ParallelDense: y[b,m,u] = relu(sum_f x[b,m,f] * W[m,f,u] + bias[m,u])
// B=2048, M=64, F=512, U=512. 64 independent GEMMs (2048x512 @ 512x512).
// bf16 MFMA (16x16x32), fp32 accumulate. 128x128 block tile, BK=32.

typedef __attribute__((ext_vector_type(8))) short bf16x8;
typedef __attribute__((ext_vector_type(4))) float f32x4;

#define LDS_S 40   // LDS leading-dim stride (elements): 16B-aligned b128 reads, no 2^n bank pattern

__device__ __forceinline__ unsigned pk_bf16(float a, float b) {
    float2 t; t.x = a; t.y = b;
    __hip_bfloat162 h = __float22bfloat162_rn(t);   // v_cvt_pk_bf16_f32 (RNE)
    union { __hip_bfloat162 h; unsigned u; } cv;
    cv.h = h;
    return cv.u;   // a in low 16, b in high 16
}

__global__ void pdense_kernel(const float* __restrict__ X,
                              const float* __restrict__ Wp,
                              const float* __restrict__ bias,
                              float* __restrict__ Out) {
    __shared__ short ldsA[128 * LDS_S];   // [row][k]  batch-rows x BK
    __shared__ short ldsB[128 * LDS_S];   // [u][k]    W^T tile (transposed at staging)

    const int tid  = threadIdx.x;
    const int lane = tid & 63;
    const int wave = tid >> 6;
    const int q    = lane >> 4;           // quad 0..3 -> k-offset q*8 in fragments
    const int ln   = lane & 15;
    const int wr   = (wave >> 1) * 64;    // wave row offset within 128-tile
    const int wc   = (wave & 1) * 64;     // wave col offset

    const int m    = blockIdx.y;
    const int bt   = blockIdx.x & 15;     // batch tile (16)
    const int ut   = blockIdx.x >> 4;     // unit tile  (4)
    const int row0 = bt * 128;
    const int col0 = ut * 128;

    // A staging: 512 chunks of 8 floats; thread handles chunks tid and tid+256.
    // chunk c -> row c>>2 (0..127), k-offset (c&3)*8
    const int ar0 = tid >> 2;
    const int ak0 = (tid & 3) * 8;
    const int ar1 = ar0 + 64;             // (tid+256)>>2
    const float* aP0 = X + (size_t)(row0 + ar0) * 32768 + m * 512 + ak0;
    const float* aP1 = X + (size_t)(row0 + ar1) * 32768 + m * 512 + ak0;

    // B staging: thread owns a 4k x 4u micro-tile; kb=t&7 spreads ds_write_b64 banks.
    const int k0 = (tid & 7) * 4;         // 0..28
    const int u0 = (tid >> 3) * 4;        // 0..124
    const float* bP = Wp + (size_t)m * 262144 + (size_t)k0 * 512 + col0 + u0;

    f32x4 acc[4][4];
    #pragma unroll
    for (int i = 0; i < 4; ++i)
        #pragma unroll
        for (int j = 0; j < 4; ++j)
            acc[i][j] = (f32x4)0.0f;

    float4 a_pre[2][2];
    float4 b_pre[4];

    // prefetch K-tile 0
    a_pre[0][0] = ((const float4*)aP0)[0];
    a_pre[0][1] = ((const float4*)aP0)[1];
    a_pre[1][0] = ((const float4*)aP1)[0];
    a_pre[1][1] = ((const float4*)aP1)[1];
    #pragma unroll
    for (int i = 0; i < 4; ++i)
        b_pre[i] = *(const float4*)(bP + (size_t)i * 512);

    for (int kt = 0; kt < 16; ++kt) {
        // ---- stage regs -> LDS (cvt to bf16; B transposed) ----
        {
            uint4 w0, w1;
            w0.x = pk_bf16(a_pre[0][0].x, a_pre[0][0].y);
            w0.y = pk_bf16(a_pre[0][0].z, a_pre[0][0].w);
            w0.z = pk_bf16(a_pre[0][1].x, a_pre[0][1].y);
            w0.w = pk_bf16(a_pre[0][1].z, a_pre[0][1].w);
            *(uint4*)&ldsA[ar0 * LDS_S + ak0] = w0;
            w1.x = pk_bf16(a_pre[1][0].x, a_pre[1][0].y);
            w1.y = pk_bf16(a_pre[1][0].z, a_pre[1][0].w);
            w1.z = pk_bf16(a_pre[1][1].x, a_pre[1][1].y);
            w1.w = pk_bf16(a_pre[1][1].z, a_pre[1][1].w);
            *(uint4*)&ldsA[ar1 * LDS_S + ak0] = w1;
            #pragma unroll
            for (int j = 0; j < 4; ++j) {   // column j of the 4x4 micro-tile
                float c0 = ((const float*)&b_pre[0])[j];
                float c1 = ((const float*)&b_pre[1])[j];
                float c2 = ((const float*)&b_pre[2])[j];
                float c3 = ((const float*)&b_pre[3])[j];
                uint2 wv;
                wv.x = pk_bf16(c0, c1);
                wv.y = pk_bf16(c2, c3);
                *(uint2*)&ldsB[(u0 + j) * LDS_S + k0] = wv;
            }
        }
        __syncthreads();

        // ---- issue next tile's global loads (latency hides behind MFMA) ----
        if (kt + 1 < 16) {
            const int ko = (kt + 1) * 32;
            a_pre[0][0] = ((const float4*)(aP0 + ko))[0];
            a_pre[0][1] = ((const float4*)(aP0 + ko))[1];
            a_pre[1][0] = ((const float4*)(aP1 + ko))[0];
            a_pre[1][1] = ((const float4*)(aP1 + ko))[1];
            #pragma unroll
            for (int i = 0; i < 4; ++i)
                b_pre[i] = *(const float4*)(bP + (size_t)(ko + i) * 512);
        }

        // ---- fragments + MFMA ----
        bf16x8 aF[4], bF[4];
        #pragma unroll
        for (int i = 0; i < 4; ++i)
            aF[i] = *(const bf16x8*)&ldsA[(wr + i * 16 + ln) * LDS_S + q * 8];
        #pragma unroll
        for (int j = 0; j < 4; ++j)
            bF[j] = *(const bf16x8*)&ldsB[(wc + j * 16 + ln) * LDS_S + q * 8];
        #pragma unroll
        for (int i = 0; i < 4; ++i)
            #pragma unroll
            for (int j = 0; j < 4; ++j)
                acc[i][j] = __builtin_amdgcn_mfma_f32_16x16x32_bf16(aF[i], bF[j], acc[i][j], 0, 0, 0);

        __syncthreads();
    }

    // ---- epilogue: bias + relu + store ----
    // D mapping (verified m89/m91): col = lane&15, row = quad*4 + reg
    #pragma unroll
    for (int j = 0; j < 4; ++j) {
        const int c = col0 + wc + j * 16 + ln;
        const float bv = bias[m * 512 + c];
        #pragma unroll
        for (int i = 0; i < 4; ++i) {
            const int r = row0 + wr + i * 16 + q * 4;
            float* op = Out + (size_t)r * 32768 + m * 512 + c;
            f32x4 v = acc[i][j];
            #pragma unroll
            for (int t = 0; t < 4; ++t) {
                float val = v[t] + bv;
                op[(size_t)t * 32768] = val > 0.0f ? val : 0.0f;
            }
        }
    }
}

extern "C" void kernel_launch(void* const* d_in, const int* in_sizes, int n_in,
                              void* d_out, int out_size, void* d_ws, size_t ws_size,
                              hipStream_t stream) {
    const float* x    = (const float*)d_in[0];   // [2048, 64, 512]
    const float* W    = (const float*)d_in[1];   // [64, 512, 512]
    const float* bias = (const float*)d_in[2];   // [64, 512]
    float* out = (float*)d_out;                  // [2048, 64*512]
    dim3 grid(64, 64);   // x: 16 batch-tiles * 4 unit-tiles; y: mask
    dim3 block(256);
    hipLaunchKernelGGL(pdense_kernel, grid, block, 0, stream, x, W, bias, out);
}

// Round 2
// 612.274 us; speedup vs baseline: 1.0079x; 1.0079x over previous
//
#include <hip/hip_runtime.h>
#include <hip/hip_bf16.h>

// ParallelDense: y[b,m,u] = relu(sum_f x[b,m,f] * W[m,f,u] + bias[m,u])
// B=2048, M=64, F=512, U=512.
// R2: prep kernel converts W fp32 [m][f][u] -> bf16 Wt [m][u][f] in d_ws;
// main GEMM: 128x128 tile, BK=32, bf16 16x16x32 MFMA, double-buffered LDS
// (1 barrier/iter), ut-fastest grid for L2 locality.

typedef __attribute__((ext_vector_type(8))) short bf16x8;
typedef __attribute__((ext_vector_type(4))) float f32x4;

#define LDS_S 40   // LDS leading-dim stride (half-words): 16B-aligned b128, ~2-way banks (free)

__device__ __forceinline__ unsigned pk_bf16(float a, float b) {
    float2 t; t.x = a; t.y = b;
    __hip_bfloat162 h = __float22bfloat162_rn(t);   // v_cvt_pk_bf16_f32 (RNE)
    union { __hip_bfloat162 h; unsigned u; } cv;
    cv.h = h;
    return cv.u;
}

// ---------------- prep: W[m][f][u] fp32 -> Wt[m][u][f] bf16 ----------------
__global__ void wt_prep_kernel(const float* __restrict__ W, short* __restrict__ Wt) {
    __shared__ float t[32][33];
    const int m  = blockIdx.z;
    const int f0 = blockIdx.y * 32;
    const int u0 = blockIdx.x * 32;
    const int tx = threadIdx.x;   // 0..31
    const int ty = threadIdx.y;   // 0..7
    const float* src = W + ((size_t)m * 512 + f0) * 512 + u0;
    #pragma unroll
    for (int i = 0; i < 4; ++i)
        t[ty + 8 * i][tx] = src[(size_t)(ty + 8 * i) * 512 + tx];
    __syncthreads();
    short* dst = Wt + ((size_t)m * 512 + u0) * 512 + f0;
    #pragma unroll
    for (int i = 0; i < 4; ++i) {
        float v = t[tx][ty + 8 * i];             // t[f][u] -> read f=tx (stride-33: conflict-free)
        dst[(size_t)(ty + 8 * i) * 512 + tx] = (short)(pk_bf16(v, v) & 0xffff);
    }
}

// ---------------- main GEMM (uses Wt) ----------------
__global__ __launch_bounds__(256) void pdense_main(const float* __restrict__ X,
                                                   const short* __restrict__ Wt,
                                                   const float* __restrict__ bias,
                                                   float* __restrict__ Out) {
    __shared__ short ldsA[2][128 * LDS_S];
    __shared__ short ldsB[2][128 * LDS_S];

    const int tid  = threadIdx.x;
    const int lane = tid & 63;
    const int wave = tid >> 6;
    const int q    = lane >> 4;           // quad -> k-offset q*8
    const int ln   = lane & 15;
    const int wr   = (wave >> 1) * 64;
    const int wc   = (wave & 1) * 64;

    const int m    = blockIdx.y;
    const int ut   = blockIdx.x & 3;      // ut fastest: blocks 0..63 = one mask
    const int bt   = blockIdx.x >> 2;
    const int row0 = bt * 128;
    const int col0 = ut * 128;

    // staging maps: 512 chunks of 16B per tile; chunk c -> row c>>2, k-off (c&3)*8
    const int r0  = tid >> 2;
    const int k8  = (tid & 3) * 8;
    const int r1  = r0 + 64;
    const float* aP0 = X + (size_t)(row0 + r0) * 32768 + m * 512 + k8;
    const float* aP1 = X + (size_t)(row0 + r1) * 32768 + m * 512 + k8;
    const short* bP0 = Wt + (size_t)m * 262144 + (size_t)(col0 + r0) * 512 + k8;
    const short* bP1 = bP0 + 64 * 512;

    f32x4 acc[4][4];
    #pragma unroll
    for (int i = 0; i < 4; ++i)
        #pragma unroll
        for (int j = 0; j < 4; ++j)
            acc[i][j] = (f32x4)0.0f;

    float4 a_pre[4];
    uint4  b_pre[2];

    // prefetch K-tile 0
    a_pre[0] = ((const float4*)aP0)[0];
    a_pre[1] = ((const float4*)aP0)[1];
    a_pre[2] = ((const float4*)aP1)[0];
    a_pre[3] = ((const float4*)aP1)[1];
    b_pre[0] = *(const uint4*)bP0;
    b_pre[1] = *(const uint4*)bP1;

    // stage tile 0 into buf 0
    {
        uint4 w0, w1;
        w0.x = pk_bf16(a_pre[0].x, a_pre[0].y);
        w0.y = pk_bf16(a_pre[0].z, a_pre[0].w);
        w0.z = pk_bf16(a_pre[1].x, a_pre[1].y);
        w0.w = pk_bf16(a_pre[1].z, a_pre[1].w);
        *(uint4*)&ldsA[0][r0 * LDS_S + k8] = w0;
        w1.x = pk_bf16(a_pre[2].x, a_pre[2].y);
        w1.y = pk_bf16(a_pre[2].z, a_pre[2].w);
        w1.z = pk_bf16(a_pre[3].x, a_pre[3].y);
        w1.w = pk_bf16(a_pre[3].z, a_pre[3].w);
        *(uint4*)&ldsA[0][r1 * LDS_S + k8] = w1;
        *(uint4*)&ldsB[0][r0 * LDS_S + k8] = b_pre[0];
        *(uint4*)&ldsB[0][r1 * LDS_S + k8] = b_pre[1];
    }

    for (int kt = 0; kt < 16; ++kt) {
        const int p = kt & 1;
        __syncthreads();   // stage(kt) visible; single barrier per iter

        // issue next tile's global loads — covered by the frag-read+MFMA phase
        if (kt + 1 < 16) {
            const int ko = (kt + 1) * 32;
            a_pre[0] = ((const float4*)(aP0 + ko))[0];
            a_pre[1] = ((const float4*)(aP0 + ko))[1];
            a_pre[2] = ((const float4*)(aP1 + ko))[0];
            a_pre[3] = ((const float4*)(aP1 + ko))[1];
            b_pre[0] = *(const uint4*)(bP0 + ko);
            b_pre[1] = *(const uint4*)(bP1 + ko);
        }

        // fragments + MFMA on buffer p
        bf16x8 aF[4], bF[4];
        #pragma unroll
        for (int i = 0; i < 4; ++i)
            aF[i] = *(const bf16x8*)&ldsA[p][(wr + i * 16 + ln) * LDS_S + q * 8];
        #pragma unroll
        for (int j = 0; j < 4; ++j)
            bF[j] = *(const bf16x8*)&ldsB[p][(wc + j * 16 + ln) * LDS_S + q * 8];
        #pragma unroll
        for (int i = 0; i < 4; ++i)
            #pragma unroll
            for (int j = 0; j < 4; ++j)
                acc[i][j] = __builtin_amdgcn_mfma_f32_16x16x32_bf16(aF[i], bF[j], acc[i][j], 0, 0, 0);

        // stage tile kt+1 into the other buffer (no barrier needed before writes:
        // readers of buf p^1 finished before barrier(kt) they already passed)
        if (kt + 1 < 16) {
            const int pn = p ^ 1;
            uint4 w0, w1;
            w0.x = pk_bf16(a_pre[0].x, a_pre[0].y);
            w0.y = pk_bf16(a_pre[0].z, a_pre[0].w);
            w0.z = pk_bf16(a_pre[1].x, a_pre[1].y);
            w0.w = pk_bf16(a_pre[1].z, a_pre[1].w);
            *(uint4*)&ldsA[pn][r0 * LDS_S + k8] = w0;
            w1.x = pk_bf16(a_pre[2].x, a_pre[2].y);
            w1.y = pk_bf16(a_pre[2].z, a_pre[2].w);
            w1.z = pk_bf16(a_pre[3].x, a_pre[3].y);
            w1.w = pk_bf16(a_pre[3].z, a_pre[3].w);
            *(uint4*)&ldsA[pn][r1 * LDS_S + k8] = w1;
            *(uint4*)&ldsB[pn][r0 * LDS_S + k8] = b_pre[0];
            *(uint4*)&ldsB[pn][r1 * LDS_S + k8] = b_pre[1];
        }
    }

    // epilogue: bias + relu + store. D map: col = lane&15, row = quad*4 + reg
    #pragma unroll
    for (int j = 0; j < 4; ++j) {
        const int c = col0 + wc + j * 16 + ln;
        const float bv = bias[m * 512 + c];
        #pragma unroll
        for (int i = 0; i < 4; ++i) {
            const int r = row0 + wr + i * 16 + q * 4;
            float* op = Out + (size_t)r * 32768 + m * 512 + c;
            f32x4 v = acc[i][j];
            #pragma unroll
            for (int t = 0; t < 4; ++t) {
                float val = v[t] + bv;
                op[(size_t)t * 32768] = val > 0.0f ? val : 0.0f;
            }
        }
    }
}

// ---------------- fallback (R1 kernel, used if ws too small) ----------------
__global__ void pdense_fallback(const float* __restrict__ X,
                                const float* __restrict__ Wp,
                                const float* __restrict__ bias,
                                float* __restrict__ Out) {
    __shared__ short ldsA[128 * LDS_S];
    __shared__ short ldsB[128 * LDS_S];

    const int tid  = threadIdx.x;
    const int lane = tid & 63;
    const int wave = tid >> 6;
    const int q    = lane >> 4;
    const int ln   = lane & 15;
    const int wr   = (wave >> 1) * 64;
    const int wc   = (wave & 1) * 64;

    const int m    = blockIdx.y;
    const int bt   = blockIdx.x & 15;
    const int ut   = blockIdx.x >> 4;
    const int row0 = bt * 128;
    const int col0 = ut * 128;

    const int ar0 = tid >> 2;
    const int ak0 = (tid & 3) * 8;
    const int ar1 = ar0 + 64;
    const float* aP0 = X + (size_t)(row0 + ar0) * 32768 + m * 512 + ak0;
    const float* aP1 = X + (size_t)(row0 + ar1) * 32768 + m * 512 + ak0;

    const int k0 = (tid & 7) * 4;
    const int u0 = (tid >> 3) * 4;
    const float* bP = Wp + (size_t)m * 262144 + (size_t)k0 * 512 + col0 + u0;

    f32x4 acc[4][4];
    #pragma unroll
    for (int i = 0; i < 4; ++i)
        #pragma unroll
        for (int j = 0; j < 4; ++j)
            acc[i][j] = (f32x4)0.0f;

    float4 a_pre[2][2];
    float4 b_pre[4];

    a_pre[0][0] = ((const float4*)aP0)[0];
    a_pre[0][1] = ((const float4*)aP0)[1];
    a_pre[1][0] = ((const float4*)aP1)[0];
    a_pre[1][1] = ((const float4*)aP1)[1];
    #pragma unroll
    for (int i = 0; i < 4; ++i)
        b_pre[i] = *(const float4*)(bP + (size_t)i * 512);

    for (int kt = 0; kt < 16; ++kt) {
        {
            uint4 w0, w1;
            w0.x = pk_bf16(a_pre[0][0].x, a_pre[0][0].y);
            w0.y = pk_bf16(a_pre[0][0].z, a_pre[0][0].w);
            w0.z = pk_bf16(a_pre[0][1].x, a_pre[0][1].y);
            w0.w = pk_bf16(a_pre[0][1].z, a_pre[0][1].w);
            *(uint4*)&ldsA[ar0 * LDS_S + ak0] = w0;
            w1.x = pk_bf16(a_pre[1][0].x, a_pre[1][0].y);
            w1.y = pk_bf16(a_pre[1][0].z, a_pre[1][0].w);
            w1.z = pk_bf16(a_pre[1][1].x, a_pre[1][1].y);
            w1.w = pk_bf16(a_pre[1][1].z, a_pre[1][1].w);
            *(uint4*)&ldsA[ar1 * LDS_S + ak0] = w1;
            #pragma unroll
            for (int j = 0; j < 4; ++j) {
                float c0 = ((const float*)&b_pre[0])[j];
                float c1 = ((const float*)&b_pre[1])[j];
                float c2 = ((const float*)&b_pre[2])[j];
                float c3 = ((const float*)&b_pre[3])[j];
                uint2 wv;
                wv.x = pk_bf16(c0, c1);
                wv.y = pk_bf16(c2, c3);
                *(uint2*)&ldsB[(u0 + j) * LDS_S + k0] = wv;
            }
        }
        __syncthreads();

        if (kt + 1 < 16) {
            const int ko = (kt + 1) * 32;
            a_pre[0][0] = ((const float4*)(aP0 + ko))[0];
            a_pre[0][1] = ((const float4*)(aP0 + ko))[1];
            a_pre[1][0] = ((const float4*)(aP1 + ko))[0];
            a_pre[1][1] = ((const float4*)(aP1 + ko))[1];
            #pragma unroll
            for (int i = 0; i < 4; ++i)
                b_pre[i] = *(const float4*)(bP + (size_t)(ko + i) * 512);
        }

        bf16x8 aF[4], bF[4];
        #pragma unroll
        for (int i = 0; i < 4; ++i)
            aF[i] = *(const bf16x8*)&ldsA[(wr + i * 16 + ln) * LDS_S + q * 8];
        #pragma unroll
        for (int j = 0; j < 4; ++j)
            bF[j] = *(const bf16x8*)&ldsB[(wc + j * 16 + ln) * LDS_S + q * 8];
        #pragma unroll
        for (int i = 0; i < 4; ++i)
            #pragma unroll
            for (int j = 0; j < 4; ++j)
                acc[i][j] = __builtin_amdgcn_mfma_f32_16x16x32_bf16(aF[i], bF[j], acc[i][j], 0, 0, 0);

        __syncthreads();
    }

    #pragma unroll
    for (int j = 0; j < 4; ++j) {
        const int c = col0 + wc + j * 16 + ln;
        const float bv = bias[m * 512 + c];
        #pragma unroll
        for (int i = 0; i < 4; ++i) {
            const int r = row0 + wr + i * 16 + q * 4;
            float* op = Out + (size_t)r * 32768 + m * 512 + c;
            f32x4 v = acc[i][j];
            #pragma unroll
            for (int t = 0; t < 4; ++t) {
                float val = v[t] + bv;
                op[(size_t)t * 32768] = val > 0.0f ? val : 0.0f;
            }
        }
    }
}

extern "C" void kernel_launch(void* const* d_in, const int* in_sizes, int n_in,
                              void* d_out, int out_size, void* d_ws, size_t ws_size,
                              hipStream_t stream) {
    const float* x    = (const float*)d_in[0];   // [2048, 64, 512]
    const float* W    = (const float*)d_in[1];   // [64, 512, 512]
    const float* bias = (const float*)d_in[2];   // [64, 512]
    float* out = (float*)d_out;                  // [2048, 64*512]

    const size_t wt_bytes = (size_t)64 * 512 * 512 * sizeof(short);  // 33.55 MB
    if (ws_size >= wt_bytes) {
        short* Wt = (short*)d_ws;
        hipLaunchKernelGGL(wt_prep_kernel, dim3(16, 16, 64), dim3(32, 8), 0, stream, W, Wt);
        hipLaunchKernelGGL(pdense_main, dim3(64, 64), dim3(256), 0, stream, x, Wt, bias, out);
    } else {
        hipLaunchKernelGGL(pdense_fallback, dim3(64, 64), dim3(256), 0, stream, W ? x : x, W, bias, out);
    }
}

// Round 3
// 597.526 us; speedup vs baseline: 1.0327x; 1.0247x over previous
//
#include <hip/hip_runtime.h>
#include <hip/hip_bf16.h>

// ParallelDense: y[b,m,u] = relu(sum_f x[b,m,f] * W[m,f,u] + bias[m,u])
// B=2048, M=64, F=512, U=512.
// R3: m97-structure GEMM. Prep converts W -> bf16 Wt[m][u][f] in d_ws.
// Main: 128x128 tile, BK=32, global_load_lds(16B) for A (fp32, XOR-swizzled)
// and B (bf16, XOR-swizzled), double-buffered LDS, 1 barrier/iter,
// XCD-aware swizzle (id&7 = XCD; 4 ut-sharers adjacent on one XCD).

typedef __attribute__((ext_vector_type(8))) short bf16x8;
typedef __attribute__((ext_vector_type(4))) float f32x4;

#define LDS_S 40   // (fallback kernel only)

__device__ __forceinline__ unsigned pk_bf16(float a, float b) {
    float2 t; t.x = a; t.y = b;
    __hip_bfloat162 h = __float22bfloat162_rn(t);   // v_cvt_pk_bf16_f32 (RNE)
    union { __hip_bfloat162 h; unsigned u; } cv;
    cv.h = h;
    return cv.u;
}

__device__ __forceinline__ void gld16(const void* g, void* l) {
    __builtin_amdgcn_global_load_lds(
        (const __attribute__((address_space(1))) void*)g,
        (__attribute__((address_space(3))) void*)l, 16, 0, 0);
}

// ---------------- prep: W[m][f][u] fp32 -> Wt[m][u][f] bf16 ----------------
__global__ void wt_prep_kernel(const float* __restrict__ W, short* __restrict__ Wt) {
    __shared__ float t[32][33];
    const int m  = blockIdx.z;
    const int f0 = blockIdx.y * 32;
    const int u0 = blockIdx.x * 32;
    const int tx = threadIdx.x;   // 0..31
    const int ty = threadIdx.y;   // 0..7
    const float* src = W + ((size_t)m * 512 + f0) * 512 + u0;
    #pragma unroll
    for (int i = 0; i < 4; ++i)
        t[ty + 8 * i][tx] = src[(size_t)(ty + 8 * i) * 512 + tx];
    __syncthreads();
    short* dst = Wt + ((size_t)m * 512 + u0) * 512 + f0;
    #pragma unroll
    for (int i = 0; i < 4; ++i) {
        float v = t[tx][ty + 8 * i];
        dst[(size_t)(ty + 8 * i) * 512 + tx] = (short)(pk_bf16(v, v) & 0xffff);
    }
}

// ---------------- main GEMM ----------------
// LDS layouts (unpadded, required by global_load_lds; XOR-swizzled for banks):
//   A: fp32, row r (128 rows) = 32 floats = 8 chunks of 16B; chunk c stored at
//      position c ^ (r&7).  Frag read (row stride 128B == 0 mod 32 banks):
//      lanes ln=0..7 hit 8 distinct bank-quads -> 2-way (free).
//   B: bf16, row r (128 rows) = 32 shorts = 4 chunks of 16B; chunk c stored at
//      position c ^ ((r>>1)&3). 2-way (free).
__global__ __launch_bounds__(256, 3) void pdense_main(const float* __restrict__ X,
                                                      const short* __restrict__ Wt,
                                                      const float* __restrict__ bias,
                                                      float* __restrict__ Out) {
    __shared__ float ldsA[2][128 * 32];   // 16 KB each
    __shared__ short ldsB[2][128 * 32];   //  8 KB each   (total 48 KB)

    const int tid  = threadIdx.x;
    const int lane = tid & 63;
    const int wave = tid >> 6;
    const int q    = lane >> 4;           // quad -> k-offset q*8
    const int ln   = lane & 15;
    const int wr   = (wave >> 1) * 64;
    const int wc   = (wave & 1) * 64;

    // XCD swizzle: id&7 = XCD (round-robin dispatch); each XCD owns 8 masks;
    // within an XCD, consecutive slots = 4 ut-blocks sharing the same x rows.
    const int id   = blockIdx.x;
    const int xcd  = id & 7;
    const int slot = id >> 3;
    const int m    = xcd * 8 + (slot >> 6);
    const int rem  = slot & 63;
    const int bt   = rem >> 2;
    const int ut   = rem & 3;
    const int row0 = bt * 128;
    const int col0 = ut * 128;

    // ---- DMA source addresses ----
    // A: 4 instrs/wave; instr i covers rows wave*32+i*8 .. +7 (8 rows x 32 fp32 = 1KB).
    //    lane l -> row (l>>3), chunk pos (l&7) -> global chunk c = (l&7) ^ (l>>3).
    const int arow = wave * 32 + (lane >> 3);
    const int ac   = (lane & 7) ^ (lane >> 3);
    const float* agp = X + (size_t)(row0 + arow) * 32768 + m * 512 + ac * 4;
    // B: 2 instrs/wave; instr j covers rows wave*32+j*16 .. +15 (16 rows x 32 bf16 = 1KB).
    //    lane l -> row (l>>2), pos (l&3) -> global chunk c = (l&3) ^ ((l>>3)&3).
    const int brow = wave * 32 + (lane >> 2);
    const int bc   = (lane & 3) ^ ((lane >> 3) & 3);
    const short* bgp = Wt + (size_t)m * 262144 + (size_t)(col0 + brow) * 512 + bc * 8;

    f32x4 acc[4][4];
    #pragma unroll
    for (int i = 0; i < 4; ++i)
        #pragma unroll
        for (int j = 0; j < 4; ++j)
            acc[i][j] = (f32x4)0.0f;

    // prologue: DMA tile 0 into buffer 0
    #pragma unroll
    for (int i = 0; i < 4; ++i)
        gld16(agp + (size_t)i * 8 * 32768, &ldsA[0][(wave * 32 + i * 8) * 32]);
    #pragma unroll
    for (int j = 0; j < 2; ++j)
        gld16(bgp + (size_t)j * 16 * 512, &ldsB[0][(wave * 32 + j * 16) * 32]);

    const int s1 = (ln >> 1) & 3;
    const int s0 = ln & 1;

    for (int kt = 0; kt < 16; ++kt) {
        const int p = kt & 1;
        __syncthreads();   // drains my DMAs (vmcnt 0) + all waves done reading buf p^1

        // DMA tile kt+1 into buf p^1 (race-free: everyone passed the barrier)
        if (kt + 1 < 16) {
            const int ko = (kt + 1) * 32;
            #pragma unroll
            for (int i = 0; i < 4; ++i)
                gld16(agp + ko + (size_t)i * 8 * 32768, &ldsA[p ^ 1][(wave * 32 + i * 8) * 32]);
            #pragma unroll
            for (int j = 0; j < 2; ++j)
                gld16(bgp + ko + (size_t)j * 16 * 512, &ldsB[p ^ 1][(wave * 32 + j * 16) * 32]);
        }

        // ---- fragments (swizzled reads) + cvt + MFMA on buf p ----
        bf16x8 aF[4], bF[4];
        #pragma unroll
        for (int i = 0; i < 4; ++i) {
            const int r = wr + i * 16 + ln;
            const float* base = &ldsA[p][r * 32 + ((q ^ s1) << 3)];
            float4 ca = *(const float4*)(base + (s0 << 2));        // k = q*8 .. +3
            float4 cb = *(const float4*)(base + ((1 - s0) << 2));  // k = q*8+4 .. +7
            union { bf16x8 v; uint4 u; } fr;
            fr.u.x = pk_bf16(ca.x, ca.y);
            fr.u.y = pk_bf16(ca.z, ca.w);
            fr.u.z = pk_bf16(cb.x, cb.y);
            fr.u.w = pk_bf16(cb.z, cb.w);
            aF[i] = fr.v;
        }
        #pragma unroll
        for (int j = 0; j < 4; ++j) {
            const int r = wc + j * 16 + ln;
            bF[j] = *(const bf16x8*)&ldsB[p][r * 32 + ((q ^ s1) << 3)];
        }
        #pragma unroll
        for (int i = 0; i < 4; ++i)
            #pragma unroll
            for (int j = 0; j < 4; ++j)
                acc[i][j] = __builtin_amdgcn_mfma_f32_16x16x32_bf16(aF[i], bF[j], acc[i][j], 0, 0, 0);
    }

    // epilogue: bias + relu + store. D map: col = lane&15, row = quad*4 + reg
    #pragma unroll
    for (int j = 0; j < 4; ++j) {
        const int c = col0 + wc + j * 16 + ln;
        const float bv = bias[m * 512 + c];
        #pragma unroll
        for (int i = 0; i < 4; ++i) {
            const int r = row0 + wr + i * 16 + q * 4;
            float* op = Out + (size_t)r * 32768 + m * 512 + c;
            f32x4 v = acc[i][j];
            #pragma unroll
            for (int t = 0; t < 4; ++t) {
                float val = v[t] + bv;
                op[(size_t)t * 32768] = val > 0.0f ? val : 0.0f;
            }
        }
    }
}

// ---------------- fallback (R1 kernel, used if ws too small) ----------------
__global__ void pdense_fallback(const float* __restrict__ X,
                                const float* __restrict__ Wp,
                                const float* __restrict__ bias,
                                float* __restrict__ Out) {
    __shared__ short ldsA[128 * LDS_S];
    __shared__ short ldsB[128 * LDS_S];

    const int tid  = threadIdx.x;
    const int lane = tid & 63;
    const int wave = tid >> 6;
    const int q    = lane >> 4;
    const int ln   = lane & 15;
    const int wr   = (wave >> 1) * 64;
    const int wc   = (wave & 1) * 64;

    const int m    = blockIdx.y;
    const int bt   = blockIdx.x & 15;
    const int ut   = blockIdx.x >> 4;
    const int row0 = bt * 128;
    const int col0 = ut * 128;

    const int ar0 = tid >> 2;
    const int ak0 = (tid & 3) * 8;
    const int ar1 = ar0 + 64;
    const float* aP0 = X + (size_t)(row0 + ar0) * 32768 + m * 512 + ak0;
    const float* aP1 = X + (size_t)(row0 + ar1) * 32768 + m * 512 + ak0;

    const int k0 = (tid & 7) * 4;
    const int u0 = (tid >> 3) * 4;
    const float* bP = Wp + (size_t)m * 262144 + (size_t)k0 * 512 + col0 + u0;

    f32x4 acc[4][4];
    #pragma unroll
    for (int i = 0; i < 4; ++i)
        #pragma unroll
        for (int j = 0; j < 4; ++j)
            acc[i][j] = (f32x4)0.0f;

    float4 a_pre[2][2];
    float4 b_pre[4];

    a_pre[0][0] = ((const float4*)aP0)[0];
    a_pre[0][1] = ((const float4*)aP0)[1];
    a_pre[1][0] = ((const float4*)aP1)[0];
    a_pre[1][1] = ((const float4*)aP1)[1];
    #pragma unroll
    for (int i = 0; i < 4; ++i)
        b_pre[i] = *(const float4*)(bP + (size_t)i * 512);

    for (int kt = 0; kt < 16; ++kt) {
        {
            uint4 w0, w1;
            w0.x = pk_bf16(a_pre[0][0].x, a_pre[0][0].y);
            w0.y = pk_bf16(a_pre[0][0].z, a_pre[0][0].w);
            w0.z = pk_bf16(a_pre[0][1].x, a_pre[0][1].y);
            w0.w = pk_bf16(a_pre[0][1].z, a_pre[0][1].w);
            *(uint4*)&ldsA[ar0 * LDS_S + ak0] = w0;
            w1.x = pk_bf16(a_pre[1][0].x, a_pre[1][0].y);
            w1.y = pk_bf16(a_pre[1][0].z, a_pre[1][0].w);
            w1.z = pk_bf16(a_pre[1][1].x, a_pre[1][1].y);
            w1.w = pk_bf16(a_pre[1][1].z, a_pre[1][1].w);
            *(uint4*)&ldsA[ar1 * LDS_S + ak0] = w1;
            #pragma unroll
            for (int j = 0; j < 4; ++j) {
                float c0 = ((const float*)&b_pre[0])[j];
                float c1 = ((const float*)&b_pre[1])[j];
                float c2 = ((const float*)&b_pre[2])[j];
                float c3 = ((const float*)&b_pre[3])[j];
                uint2 wv;
                wv.x = pk_bf16(c0, c1);
                wv.y = pk_bf16(c2, c3);
                *(uint2*)&ldsB[(u0 + j) * LDS_S + k0] = wv;
            }
        }
        __syncthreads();

        if (kt + 1 < 16) {
            const int ko = (kt + 1) * 32;
            a_pre[0][0] = ((const float4*)(aP0 + ko))[0];
            a_pre[0][1] = ((const float4*)(aP0 + ko))[1];
            a_pre[1][0] = ((const float4*)(aP1 + ko))[0];
            a_pre[1][1] = ((const float4*)(aP1 + ko))[1];
            #pragma unroll
            for (int i = 0; i < 4; ++i)
                b_pre[i] = *(const float4*)(bP + (size_t)(ko + i) * 512);
        }

        bf16x8 aF[4], bF[4];
        #pragma unroll
        for (int i = 0; i < 4; ++i)
            aF[i] = *(const bf16x8*)&ldsA[(wr + i * 16 + ln) * LDS_S + q * 8];
        #pragma unroll
        for (int j = 0; j < 4; ++j)
            bF[j] = *(const bf16x8*)&ldsB[(wc + j * 16 + ln) * LDS_S + q * 8];
        #pragma unroll
        for (int i = 0; i < 4; ++i)
            #pragma unroll
            for (int j = 0; j < 4; ++j)
                acc[i][j] = __builtin_amdgcn_mfma_f32_16x16x32_bf16(aF[i], bF[j], acc[i][j], 0, 0, 0);

        __syncthreads();
    }

    #pragma unroll
    for (int j = 0; j < 4; ++j) {
        const int c = col0 + wc + j * 16 + ln;
        const float bv = bias[m * 512 + c];
        #pragma unroll
        for (int i = 0; i < 4; ++i) {
            const int r = row0 + wr + i * 16 + q * 4;
            float* op = Out + (size_t)r * 32768 + m * 512 + c;
            f32x4 v = acc[i][j];
            #pragma unroll
            for (int t = 0; t < 4; ++t) {
                float val = v[t] + bv;
                op[(size_t)t * 32768] = val > 0.0f ? val : 0.0f;
            }
        }
    }
}

extern "C" void kernel_launch(void* const* d_in, const int* in_sizes, int n_in,
                              void* d_out, int out_size, void* d_ws, size_t ws_size,
                              hipStream_t stream) {
    const float* x    = (const float*)d_in[0];   // [2048, 64, 512]
    const float* W    = (const float*)d_in[1];   // [64, 512, 512]
    const float* bias = (const float*)d_in[2];   // [64, 512]
    float* out = (float*)d_out;                  // [2048, 64*512]

    const size_t wt_bytes = (size_t)64 * 512 * 512 * sizeof(short);  // 33.55 MB
    if (ws_size >= wt_bytes) {
        short* Wt = (short*)d_ws;
        hipLaunchKernelGGL(wt_prep_kernel, dim3(16, 16, 64), dim3(32, 8), 0, stream, W, Wt);
        hipLaunchKernelGGL(pdense_main, dim3(4096), dim3(256), 0, stream, x, Wt, bias, out);
    } else {
        hipLaunchKernelGGL(pdense_fallback, dim3(64, 64), dim3(256), 0, stream, x, W, bias, out);
    }
}